// Round 7
// baseline (3942.992 us; speedup 1.0000x reference)
//
#include <hip/hip_runtime.h>
#include <hip/hip_bf16.h>

#define S_ 8
#define B_ 32
#define T_ 512
#define I_ 256
#define H_ 512
#define O_ 32

typedef __attribute__((ext_vector_type(8))) short short8;
typedef __attribute__((ext_vector_type(4))) float float4_;

__device__ __forceinline__ unsigned short f2bf(float f) {
    unsigned u = __float_as_uint(f);
    u = (u + 0x7fffu + ((u >> 16) & 1u)) >> 16;   // RNE
    return (unsigned short)u;
}
__device__ __forceinline__ short8 cvt2(float4_ a, float4_ b) {
    short8 r;
    r[0]=(short)f2bf(a[0]); r[1]=(short)f2bf(a[1]); r[2]=(short)f2bf(a[2]); r[3]=(short)f2bf(a[3]);
    r[4]=(short)f2bf(b[0]); r[5]=(short)f2bf(b[1]); r[6]=(short)f2bf(b[2]); r[7]=(short)f2bf(b[3]);
    return r;
}
__device__ __forceinline__ short8 load_cvt8(const float* p) {
    return cvt2(*reinterpret_cast<const float4_*>(p), *reinterpret_cast<const float4_*>(p + 4));
}

// Agent-coherent accesses (sc0 sc1 -> device coherence point / LLC). This is
// the PROVEN transport (R2-R4 passed; sc0-only falsified in R6). Loads are
// valid only after s_waitcnt vmcnt(0).
__device__ __forceinline__ float4_ ld16f(const float* p) {
    float4_ v;
    asm volatile("global_load_dwordx4 %0, %1, off sc0 sc1" : "=v"(v) : "v"(p) : "memory");
    return v;
}
__device__ __forceinline__ void st16f(float* p, float4_ v) {
    asm volatile("global_store_dwordx4 %0, %1, off sc0 sc1" :: "v"(p), "v"(v) : "memory");
}
__device__ __forceinline__ void vm0() {
    asm volatile("s_waitcnt vmcnt(0)" ::: "memory");
    __builtin_amdgcn_sched_barrier(0);   // rule #18
}

// ws layout (bytes):
//   [0, 1048576)         : h fp32(+2-bit tag) double buffer [2][S][B][H]
//   [1048576, 1064960)   : hbar fp32 [S][H]
//   [1064960, 1067008)   : done counters, uint per seq, 256B stride
#define WS_NEED 1067008

__global__ __launch_bounds__(256, 1)
void zgru_persistent(const float* __restrict__ x, const int* __restrict__ lens,
                     const float* __restrict__ Wih, const float* __restrict__ Whh,
                     const float* __restrict__ bih, const float* __restrict__ bhh,
                     const float* __restrict__ Wout, const float* __restrict__ bout,
                     float* __restrict__ out,
                     float* __restrict__ hbufF, float* __restrict__ hbar,
                     unsigned* __restrict__ done_ctr)
{
    const int tid  = threadIdx.x;
    const int wg   = blockIdx.x;
    const int s    = wg & 7;         // round-robin -> seq co-located-ish, L2-friendly x reads
    const int j    = wg >> 3;        // hidden-col group: cols [16j, 16j+16)
    const int wid  = tid >> 6;
    const int lane = tid & 63;
    const int m    = wid >> 1;       // batch half (rows 16m..16m+15)
    const int kh   = wid & 1;        // K half
    const int lrow = lane & 15;
    const int lgrp = lane >> 4;

    const int len = lens[s];

    // ---- LDS ------------------------------------------------------------
    __shared__ unsigned short whh_lds[48 * 512];   // W_hh bf16 B-fragments
    __shared__ float4_ xch[2][4][64];              // [m][gate][lane] partials
    __shared__ float hshF[2][16][16];              // tagged-f32 transpose staging
    __shared__ unsigned fxch[2];                   // kh1 -> kh0 tokens per m
    __shared__ unsigned last_flag;
    __shared__ float red[8][32];

    for (int gi = tid; gi < 48 * 64; gi += 256) {
        const int blk = gi >> 6, ln = gi & 63;
        const int khb = blk / 24, rem = blk % 24;
        const int g = rem >> 3, kc = rem & 7;
        const int lg = ln >> 4, lc = ln & 15;
        const float* src = Whh + (size_t)(g * H_ + 16 * j + lc) * H_
                         + 256 * khb + 32 * kc + 8 * lg;
        *reinterpret_cast<short8*>(&whh_lds[(size_t)blk * 512 + ln * 8]) = load_cvt8(src);
    }
    if (tid < 2) fxch[tid] = 0;

    short8 bxR[4], bxZ[4], bxN[4];
    {
        const int gr = 16 * j + lrow;
        #pragma unroll
        for (int kc = 0; kc < 4; ++kc) {
            const int k0 = 128 * kh + 32 * kc + 8 * lgrp;
            bxR[kc] = load_cvt8(Wih + (size_t)(gr          ) * I_ + k0);
            bxZ[kc] = load_cvt8(Wih + (size_t)(gr +     H_ ) * I_ + k0);
            bxN[kc] = load_cvt8(Wih + (size_t)(gr + 2 * H_ ) * I_ + k0);
        }
    }

    const int gcol   = 16 * j + lrow;
    const float bsR  = bih[gcol] + bhh[gcol];
    const float bsZ  = bih[H_ + gcol] + bhh[H_ + gcol];
    const float biN  = bih[2 * H_ + gcol];
    const float bhN_ = bhh[2 * H_ + gcol];

    __syncthreads();   // whh_lds + fxch ready

    float h[4] = {0.f, 0.f, 0.f, 0.f};

    const size_t HBUFF = (size_t)S_ * B_ * H_;   // f32 elements per buffer
    const int arow = 16 * m + lrow;
    const float* xlane = x + ((size_t)s * B_ + arow) * T_ * I_ + 128 * kh + 8 * lgrp;
    const float* hrF0  = hbufF + ((size_t)s * B_ + arow) * H_ + 256 * kh + 8 * lgrp;
    float*       hwF0  = hbufF + ((size_t)s * B_ + 16 * m) * H_ + 16 * j;

    // prime x prefetch for t=0 (plain loads; compiler manages their waits)
    float4_ xraw[8];
    {
        const float* xp = xlane;
        #pragma unroll
        for (int kc = 0; kc < 4; ++kc) {
            xraw[2*kc]   = *reinterpret_cast<const float4_*>(xp + 32*kc);
            xraw[2*kc+1] = *reinterpret_cast<const float4_*>(xp + 32*kc + 4);
        }
    }

    for (int t = 0; t < len; ++t) {
        // ---- x part (recurrence-independent, uses prefetched x(t)) ------
        short8 ax[4];
        #pragma unroll
        for (int kc = 0; kc < 4; ++kc) ax[kc] = cvt2(xraw[2*kc], xraw[2*kc+1]);
        float4_ aR = {0,0,0,0}, aZ = {0,0,0,0}, aNX = {0,0,0,0};
        #pragma unroll
        for (int kc = 0; kc < 4; ++kc) {
            aR  = __builtin_amdgcn_mfma_f32_16x16x32_bf16(ax[kc], bxR[kc], aR, 0, 0, 0);
            aZ  = __builtin_amdgcn_mfma_f32_16x16x32_bf16(ax[kc], bxZ[kc], aZ, 0, 0, 0);
            aNX = __builtin_amdgcn_mfma_f32_16x16x32_bf16(ax[kc], bxN[kc], aNX, 0, 0, 0);
        }

        // ---- self-validating h poll: data IS the flag -------------------
        // Every f32 of tile h(t) carries tag = t&3 in mantissa bits [1:0].
        // Stale (t-2, same buffer) differs in bit1; partial writes detected
        // per-dword. Structural skew bound <=1 prevents t+2 overwrite while
        // any reader of t is pending.
        const float* hrF = hrF0 + (size_t)(t & 1) * HBUFF;
        const unsigned tag = (unsigned)t & 3u;
        float4_ hraw[16];
        for (int it = 0; it < (1 << 19); ++it) {
            #pragma unroll
            for (int kc = 0; kc < 8; ++kc) {
                hraw[2*kc]   = ld16f(hrF + 32 * kc);
                hraw[2*kc+1] = ld16f(hrF + 32 * kc + 4);
            }
            vm0();
            unsigned acc = 0;
            #pragma unroll
            for (int q = 0; q < 16; ++q)
                #pragma unroll
                for (int e = 0; e < 4; ++e)
                    acc |= (__float_as_uint(hraw[q][e]) ^ tag);
            if (__ballot((acc & 3u) == 0u) == ~0ull) break;
        }

        // ---- x refill for t+1 (issued after poll so poll never waits x) --
        {
            const int tn = (t + 1 < len) ? (t + 1) : t;
            const float* xp = xlane + (size_t)tn * I_;
            #pragma unroll
            for (int kc = 0; kc < 4; ++kc) {
                xraw[2*kc]   = *reinterpret_cast<const float4_*>(xp + 32*kc);
                xraw[2*kc+1] = *reinterpret_cast<const float4_*>(xp + 32*kc + 4);
            }
        }

        // ---- h MFMAs (tag bits vanish in f32->bf16 RNE) ------------------
        short8 ah[8];
        #pragma unroll
        for (int kc = 0; kc < 8; ++kc) ah[kc] = cvt2(hraw[2*kc], hraw[2*kc+1]);
        float4_ aNH = {0,0,0,0};
        #pragma unroll
        for (int kc = 0; kc < 8; ++kc) {
            short8 bR = *reinterpret_cast<const short8*>(&whh_lds[(size_t)(kh*24 + kc     ) * 512 + lane * 8]);
            short8 bZ = *reinterpret_cast<const short8*>(&whh_lds[(size_t)(kh*24 + kc +  8) * 512 + lane * 8]);
            short8 bN = *reinterpret_cast<const short8*>(&whh_lds[(size_t)(kh*24 + kc + 16) * 512 + lane * 8]);
            aR  = __builtin_amdgcn_mfma_f32_16x16x32_bf16(ah[kc], bR, aR,  0, 0, 0);
            aZ  = __builtin_amdgcn_mfma_f32_16x16x32_bf16(ah[kc], bZ, aZ,  0, 0, 0);
            aNH = __builtin_amdgcn_mfma_f32_16x16x32_bf16(ah[kc], bN, aNH, 0, 0, 0);
        }

        if (kh == 1) {   // hand partials to kh==0 via LDS + release token
            xch[m][0][lane] = aR;
            xch[m][1][lane] = aZ;
            xch[m][2][lane] = aNH;
            xch[m][3][lane] = aNX;
            __hip_atomic_store(&fxch[m], (unsigned)(t + 1),
                               __ATOMIC_RELEASE, __HIP_MEMORY_SCOPE_WORKGROUP);
        } else {         // kh==0: merge, gates, tagged-f32 publish
            for (int it = 0; it < (1 << 20); ++it) {
                if (__hip_atomic_load(&fxch[m], __ATOMIC_ACQUIRE,
                                      __HIP_MEMORY_SCOPE_WORKGROUP) >= (unsigned)(t + 1)) break;
            }
            __builtin_amdgcn_sched_barrier(0);
            aR  += xch[m][0][lane];
            aZ  += xch[m][1][lane];
            aNH += xch[m][2][lane];
            aNX += xch[m][3][lane];

            const unsigned wtag = (unsigned)(t + 1) & 3u;
            #pragma unroll
            for (int i = 0; i < 4; ++i) {
                const float pr = aR[i] + bsR;
                const float pz = aZ[i] + bsZ;
                const float r = 1.f / (1.f + __expf(-pr));
                const float z = 1.f / (1.f + __expf(-pz));
                const float pn = aNX[i] + biN + r * (aNH[i] + bhN_);
                const float e = __expf(-2.f * fabsf(pn));
                float n = (1.f - e) / (1.f + e);
                n = copysignf(n, pn);
                h[i] = z * (h[i] - n) + n;
                const unsigned u = (__float_as_uint(h[i]) & ~3u) | wtag;   // embed tag
                hshF[m][4 * lgrp + i][lrow] = __uint_as_float(u);          // transpose stage
            }
            // compiler inserts the LDS waits (write->read same array)
            float* hwF = hwF0 + (size_t)((t + 1) & 1) * HBUFF;
            const int row = lane >> 2, c4 = (lane & 3) * 4;
            float4_ v = *reinterpret_cast<const float4_*>(&hshF[m][row][c4]);
            st16f(hwF + (size_t)row * H_ + c4, v);   // fire-and-forget; consumers self-validate
        }
    }

    // ---- hbar[s][col] = sum_b h -----------------------------------------
    float s4 = h[0] + h[1] + h[2] + h[3];
    s4 += __shfl_xor(s4, 16);
    s4 += __shfl_xor(s4, 32);
    if (kh == 0 && lgrp == 0)
        atomicAdd(&hbar[(size_t)s * H_ + gcol], s4);   // device-scope

    __syncthreads();   // drains atomics before done signal
    if (tid == 0) {
        unsigned old = __hip_atomic_fetch_add(&done_ctr[s * 64], 1u,
                                              __ATOMIC_RELAXED, __HIP_MEMORY_SCOPE_AGENT);
        last_flag = (old == 31u) ? 1u : 0u;
    }
    __syncthreads();
    if (last_flag) {   // last WG of this sequence computes the output row
        const int o = tid & 31;
        const int p = tid >> 5;
        float acc = 0.f;
        const float* hb = hbar + (size_t)s * H_;
        const float* wr = Wout + (size_t)o * H_;
        for (int hh = 64 * p; hh < 64 * p + 64; ++hh) {
            float hv = __hip_atomic_load(&hb[hh], __ATOMIC_RELAXED, __HIP_MEMORY_SCOPE_AGENT);
            acc += hv * wr[hh];
        }
        red[p][o] = acc;
        __syncthreads();
        if (tid < 32) {
            float v = 0.f;
            #pragma unroll
            for (int q = 0; q < 8; ++q) v += red[q][tid];
            out[s * O_ + tid] = v * (1.f / 32.f) + bout[tid];
        }
    }
}

extern "C" void kernel_launch(void* const* d_in, const int* in_sizes, int n_in,
                              void* d_out, int out_size, void* d_ws, size_t ws_size,
                              hipStream_t stream) {
    (void)in_sizes; (void)n_in; (void)out_size; (void)ws_size;
    const float* x    = (const float*)d_in[0];
    const int*   lens = (const int*)d_in[1];
    const float* Wih  = (const float*)d_in[2];
    const float* Whh  = (const float*)d_in[3];
    const float* bih  = (const float*)d_in[4];
    const float* bhh  = (const float*)d_in[5];
    const float* Wout = (const float*)d_in[6];
    const float* bout = (const float*)d_in[7];
    float* out = (float*)d_out;

    char* wsc = (char*)d_ws;
    float*    hbufF = (float*)wsc;
    float*    hbar  = (float*)(wsc + 1048576);
    unsigned* dctr  = (unsigned*)(wsc + 1064960);

    // zero h buffers (tag 0 == valid h(0)=0) + hbar + done counters
    hipMemsetAsync(d_ws, 0, WS_NEED, stream);

    zgru_persistent<<<dim3(256), dim3(256), 0, stream>>>(
        x, lens, Wih, Whh, bih, bhh, Wout, bout, out, hbufF, hbar, dctr);
}

// Round 8
// 2366.645 us; speedup vs baseline: 1.6661x; 1.6661x over previous
//
#include <hip/hip_runtime.h>
#include <hip/hip_bf16.h>

#define S_ 8
#define B_ 32
#define T_ 512
#define I_ 256
#define H_ 512
#define O_ 32

typedef __attribute__((ext_vector_type(8))) short short8;
typedef __attribute__((ext_vector_type(4))) float float4_;

__device__ __forceinline__ unsigned short f2bf(float f) {
    unsigned u = __float_as_uint(f);
    u = (u + 0x7fffu + ((u >> 16) & 1u)) >> 16;   // RNE
    return (unsigned short)u;
}
__device__ __forceinline__ short8 cvt2(float4_ a, float4_ b) {
    short8 r;
    r[0]=(short)f2bf(a[0]); r[1]=(short)f2bf(a[1]); r[2]=(short)f2bf(a[2]); r[3]=(short)f2bf(a[3]);
    r[4]=(short)f2bf(b[0]); r[5]=(short)f2bf(b[1]); r[6]=(short)f2bf(b[2]); r[7]=(short)f2bf(b[3]);
    return r;
}
__device__ __forceinline__ short8 load_cvt8(const float* p) {
    return cvt2(*reinterpret_cast<const float4_*>(p), *reinterpret_cast<const float4_*>(p + 4));
}

// PROVEN transport: sc0 sc1 -> device coherence point. Loads valid only after
// s_waitcnt vmcnt; flags tiny (<=1 line per poll).
__device__ __forceinline__ short8 ld16c(const unsigned short* p) {
    short8 v;
    asm volatile("global_load_dwordx4 %0, %1, off sc0 sc1" : "=v"(v) : "v"(p) : "memory");
    return v;
}
__device__ __forceinline__ unsigned ldu32c(const unsigned* p) {
    unsigned v;
    asm volatile("global_load_dword %0, %1, off sc0 sc1" : "=v"(v) : "v"(p) : "memory");
    return v;
}
__device__ __forceinline__ void st16c(unsigned short* p, short8 v) {
    asm volatile("global_store_dwordx4 %0, %1, off sc0 sc1" :: "v"(p), "v"(v) : "memory");
}
__device__ __forceinline__ void stu32c(unsigned* p, unsigned v) {
    asm volatile("global_store_dword %0, %1, off sc0 sc1" :: "v"(p), "v"(v) : "memory");
}
__device__ __forceinline__ void vm0() {
    asm volatile("s_waitcnt vmcnt(0)" ::: "memory");
    __builtin_amdgcn_sched_barrier(0);   // rule #18
}

// ws layout (bytes):
//   [0, 524288)        : h bf16 double buffer [2][S][B][H]
//   [524288, 540672)   : hbar fp32 [S][H]
//   [540672, 544768)   : flags uint [S][2][64]  (256B-aligned per (s,m); idx j*2+kh)
//   [544768, 546816)   : done counters, uint per seq, 256B stride
#define WS_NEED 546816

__global__ __launch_bounds__(256, 1)
void zgru_persistent(const float* __restrict__ x, const int* __restrict__ lens,
                     const float* __restrict__ Wih, const float* __restrict__ Whh,
                     const float* __restrict__ bih, const float* __restrict__ bhh,
                     const float* __restrict__ Wout, const float* __restrict__ bout,
                     float* __restrict__ out,
                     unsigned short* __restrict__ hbuf, float* __restrict__ hbar,
                     unsigned* __restrict__ flags, unsigned* __restrict__ done_ctr)
{
    const int tid  = threadIdx.x;
    const int wg   = blockIdx.x;
    const int s    = wg & 7;         // round-robin -> L2-friendly co-location
    const int j    = wg >> 3;        // hidden-col group: cols [16j, 16j+16)
    const int wid  = tid >> 6;
    const int lane = tid & 63;
    const int m    = wid >> 1;       // batch half (rows 16m..16m+15)
    const int kh   = wid & 1;        // K half; also row-half owner (rows kh*8..+8)
    const int lrow = lane & 15;
    const int lgrp = lane >> 4;

    const int len = lens[s];

    // ---- LDS ------------------------------------------------------------
    __shared__ unsigned short whh_lds[48 * 512];     // W_hh bf16 B-fragments
    __shared__ float4_ xch[2][2][4][32];             // [m][src_kh][gate][slot]
    __shared__ __align__(16) unsigned short hsh[4][8][16];  // [m*2+kh][row][col]
    __shared__ unsigned fxch[2][2];                  // [m][kh] exchange tokens
    __shared__ unsigned last_flag;
    __shared__ float red[8][32];

    for (int gi = tid; gi < 48 * 64; gi += 256) {
        const int blk = gi >> 6, ln = gi & 63;
        const int khb = blk / 24, rem = blk % 24;
        const int g = rem >> 3, kc = rem & 7;
        const int lg = ln >> 4, lc = ln & 15;
        const float* src = Whh + (size_t)(g * H_ + 16 * j + lc) * H_
                         + 256 * khb + 32 * kc + 8 * lg;
        *reinterpret_cast<short8*>(&whh_lds[(size_t)blk * 512 + ln * 8]) = load_cvt8(src);
    }
    if (tid < 4) fxch[tid >> 1][tid & 1] = 0;

    short8 bxR[4], bxZ[4], bxN[4];
    {
        const int gr = 16 * j + lrow;
        #pragma unroll
        for (int kc = 0; kc < 4; ++kc) {
            const int k0 = 128 * kh + 32 * kc + 8 * lgrp;
            bxR[kc] = load_cvt8(Wih + (size_t)(gr          ) * I_ + k0);
            bxZ[kc] = load_cvt8(Wih + (size_t)(gr +     H_ ) * I_ + k0);
            bxN[kc] = load_cvt8(Wih + (size_t)(gr + 2 * H_ ) * I_ + k0);
        }
    }

    const int gcol   = 16 * j + lrow;
    const float bsR  = bih[gcol] + bhh[gcol];
    const float bsZ  = bih[H_ + gcol] + bhh[H_ + gcol];
    const float biN  = bih[2 * H_ + gcol];
    const float bhN_ = bhh[2 * H_ + gcol];

    __syncthreads();   // whh_lds + fxch ready

    float h[4] = {0.f, 0.f, 0.f, 0.f};

    const size_t HBUF = (size_t)S_ * B_ * H_;
    const int arow = 16 * m + lrow;
    const float* xlane = x + ((size_t)s * B_ + arow) * T_ * I_ + 128 * kh + 8 * lgrp;
    const unsigned short* hrow = hbuf + ((size_t)s * B_ + arow) * H_ + 256 * kh + 8 * lgrp;
    const unsigned* fl = flags + (size_t)(s * 2 + m) * 64;
    unsigned* myflag   = flags + (size_t)(s * 2 + m) * 64 + j * 2 + kh;

    // role split: this wave owns batch rows kh*8..kh*8+8 of its m-half
    const bool active = (kh == 0) ? (lane < 32) : (lane >= 32);
    const bool writer = !active;                       // lanes holding partner's rows
    const int  wslot  = (kh == 0) ? lane - 32 : lane;  // valid when writer
    const int  rslot  = (kh == 0) ? lane      : lane - 32;  // valid when active
    const unsigned pl = (unsigned)(lane - kh * 32);    // publish lane id, <16 publishes
    const int  q      = m * 2 + kh;                    // hsh slot

    // prime x prefetch for t=0
    float4_ xraw[8];
    {
        const float* xp = xlane;
        #pragma unroll
        for (int kc = 0; kc < 4; ++kc) {
            xraw[2*kc]   = *reinterpret_cast<const float4_*>(xp + 32*kc);
            xraw[2*kc+1] = *reinterpret_cast<const float4_*>(xp + 32*kc + 4);
        }
    }

    for (int t = 0; t < len; ++t) {
        // ---- x part from prefetch; refill xraw for t+1 immediately -------
        short8 ax[4];
        #pragma unroll
        for (int kc = 0; kc < 4; ++kc) ax[kc] = cvt2(xraw[2*kc], xraw[2*kc+1]);
        {
            const int tn = (t + 1 < len) ? (t + 1) : t;
            const float* xp = xlane + (size_t)tn * I_;
            #pragma unroll
            for (int kc = 0; kc < 4; ++kc) {
                xraw[2*kc]   = *reinterpret_cast<const float4_*>(xp + 32*kc);
                xraw[2*kc+1] = *reinterpret_cast<const float4_*>(xp + 32*kc + 4);
            }
        }
        float4_ aR = {0,0,0,0}, aZ = {0,0,0,0}, aNX = {0,0,0,0};
        #pragma unroll
        for (int kc = 0; kc < 4; ++kc) {
            aR  = __builtin_amdgcn_mfma_f32_16x16x32_bf16(ax[kc], bxR[kc], aR, 0, 0, 0);
            aZ  = __builtin_amdgcn_mfma_f32_16x16x32_bf16(ax[kc], bxZ[kc], aZ, 0, 0, 0);
            aNX = __builtin_amdgcn_mfma_f32_16x16x32_bf16(ax[kc], bxN[kc], aNX, 0, 0, 0);
        }

        // ---- pipelined 2-deep flag poll (64 flags = one line) ------------
        if (t > 0) {
            const unsigned tgt = (unsigned)t;
            unsigned fa = ldu32c(fl + lane);
            bool done = false;
            for (int it = 0; it < (1 << 15) && !done; ++it) {
                unsigned fb = ldu32c(fl + lane);
                asm volatile("s_waitcnt vmcnt(1)" ::: "memory");  // fa (+ stale x) done
                __builtin_amdgcn_sched_barrier(0);
                if (__ballot(fa >= tgt) == ~0ull) { done = true; break; }
                fa = ldu32c(fl + lane);
                asm volatile("s_waitcnt vmcnt(1)" ::: "memory");  // fb done
                __builtin_amdgcn_sched_barrier(0);
                if (__ballot(fb >= tgt) == ~0ull) done = true;
            }
            vm0();   // drain leftover poll load -> clean counts for h loads
        }

        // ---- h loads with counted waits; MFMAs start at half-arrival -----
        const unsigned short* hr = hrow + (size_t)(t & 1) * HBUF;
        short8 ah[8];
        #pragma unroll
        for (int kc = 0; kc < 8; ++kc) ah[kc] = ld16c(hr + 32 * kc);
        asm volatile("s_waitcnt vmcnt(4)" ::: "memory");   // ah[0..3] valid
        __builtin_amdgcn_sched_barrier(0);
        float4_ aNH = {0,0,0,0};
        #pragma unroll
        for (int kc = 0; kc < 4; ++kc) {
            short8 bR = *reinterpret_cast<const short8*>(&whh_lds[(size_t)(kh*24 + kc     ) * 512 + lane * 8]);
            short8 bZ = *reinterpret_cast<const short8*>(&whh_lds[(size_t)(kh*24 + kc +  8) * 512 + lane * 8]);
            short8 bN = *reinterpret_cast<const short8*>(&whh_lds[(size_t)(kh*24 + kc + 16) * 512 + lane * 8]);
            aR  = __builtin_amdgcn_mfma_f32_16x16x32_bf16(ah[kc], bR, aR,  0, 0, 0);
            aZ  = __builtin_amdgcn_mfma_f32_16x16x32_bf16(ah[kc], bZ, aZ,  0, 0, 0);
            aNH = __builtin_amdgcn_mfma_f32_16x16x32_bf16(ah[kc], bN, aNH, 0, 0, 0);
        }
        asm volatile("s_waitcnt vmcnt(0)" ::: "memory");   // ah[4..7] valid
        __builtin_amdgcn_sched_barrier(0);
        #pragma unroll
        for (int kc = 4; kc < 8; ++kc) {
            short8 bR = *reinterpret_cast<const short8*>(&whh_lds[(size_t)(kh*24 + kc     ) * 512 + lane * 8]);
            short8 bZ = *reinterpret_cast<const short8*>(&whh_lds[(size_t)(kh*24 + kc +  8) * 512 + lane * 8]);
            short8 bN = *reinterpret_cast<const short8*>(&whh_lds[(size_t)(kh*24 + kc + 16) * 512 + lane * 8]);
            aR  = __builtin_amdgcn_mfma_f32_16x16x32_bf16(ah[kc], bR, aR,  0, 0, 0);
            aZ  = __builtin_amdgcn_mfma_f32_16x16x32_bf16(ah[kc], bZ, aZ,  0, 0, 0);
            aNH = __builtin_amdgcn_mfma_f32_16x16x32_bf16(ah[kc], bN, aNH, 0, 0, 0);
        }

        // ---- symmetric partial exchange: each wave keeps its row-half ----
        if (writer) {
            xch[m][kh][0][wslot] = aR;
            xch[m][kh][1][wslot] = aZ;
            xch[m][kh][2][wslot] = aNH;
            xch[m][kh][3][wslot] = aNX;
        }
        if (lane == 0)
            __hip_atomic_store(&fxch[m][kh], (unsigned)(t + 1),
                               __ATOMIC_RELEASE, __HIP_MEMORY_SCOPE_WORKGROUP);
        for (int it = 0; it < (1 << 20); ++it) {
            if (__hip_atomic_load(&fxch[m][kh ^ 1], __ATOMIC_ACQUIRE,
                                  __HIP_MEMORY_SCOPE_WORKGROUP) >= (unsigned)(t + 1)) break;
        }
        __builtin_amdgcn_sched_barrier(0);

        // ---- gates + publish, both kh-waves in parallel ------------------
        if (active) {
            aR  += xch[m][kh ^ 1][0][rslot];
            aZ  += xch[m][kh ^ 1][1][rslot];
            aNH += xch[m][kh ^ 1][2][rslot];
            aNX += xch[m][kh ^ 1][3][rslot];
            #pragma unroll
            for (int i = 0; i < 4; ++i) {
                const float pr = aR[i] + bsR;
                const float pz = aZ[i] + bsZ;
                const float r = 1.f / (1.f + __expf(-pr));
                const float z = 1.f / (1.f + __expf(-pz));
                const float pn = aNX[i] + biN + r * (aNH[i] + bhN_);
                const float e = __expf(-2.f * fabsf(pn));
                float n = (1.f - e) / (1.f + e);
                n = copysignf(n, pn);
                h[i] = z * (h[i] - n) + n;
                hsh[q][(lgrp & 1) * 4 + i][lrow] = f2bf(h[i]);   // transpose stage
            }
        }
        asm volatile("s_waitcnt lgkmcnt(0)" ::: "memory");
        __builtin_amdgcn_sched_barrier(0);
        if (pl < 16u) {   // 16B/lane coalesced publish of this wave's 8x16 tile
            const int rr = (int)(pl >> 1), pc = (int)(pl & 1) * 8;
            short8 v = *reinterpret_cast<const short8*>(&hsh[q][rr][pc]);
            st16c(hbuf + (size_t)((t + 1) & 1) * HBUF
                       + ((size_t)s * B_ + 16 * m + 8 * kh + rr) * H_ + 16 * j + pc, v);
        }
        vm0();   // tile at coherence point
        if (lane == kh * 32) stu32c(myflag, (unsigned)(t + 1));
    }

    // ---- hbar[s][col] = sum over this wave's 8 rows ----------------------
    float s4 = h[0] + h[1] + h[2] + h[3];
    s4 += __shfl_xor(s4, 16);            // combine lgrp pair within the half
    if (pl < 16u)
        atomicAdd(&hbar[(size_t)s * H_ + gcol], s4);   // device-scope

    __syncthreads();   // drains atomics before done signal
    if (tid == 0) {
        unsigned old = __hip_atomic_fetch_add(&done_ctr[s * 64], 1u,
                                              __ATOMIC_RELAXED, __HIP_MEMORY_SCOPE_AGENT);
        last_flag = (old == 31u) ? 1u : 0u;
    }
    __syncthreads();
    if (last_flag) {   // last WG of this sequence computes the output row
        const int o = tid & 31;
        const int p = tid >> 5;
        float acc = 0.f;
        const float* hb = hbar + (size_t)s * H_;
        const float* wr = Wout + (size_t)o * H_;
        for (int hh = 64 * p; hh < 64 * p + 64; ++hh) {
            float hv = __hip_atomic_load(&hb[hh], __ATOMIC_RELAXED, __HIP_MEMORY_SCOPE_AGENT);
            acc += hv * wr[hh];
        }
        red[p][o] = acc;
        __syncthreads();
        if (tid < 32) {
            float v = 0.f;
            #pragma unroll
            for (int qq = 0; qq < 8; ++qq) v += red[qq][tid];
            out[s * O_ + tid] = v * (1.f / 32.f) + bout[tid];
        }
    }
}

extern "C" void kernel_launch(void* const* d_in, const int* in_sizes, int n_in,
                              void* d_out, int out_size, void* d_ws, size_t ws_size,
                              hipStream_t stream) {
    (void)in_sizes; (void)n_in; (void)out_size; (void)ws_size;
    const float* x    = (const float*)d_in[0];
    const int*   lens = (const int*)d_in[1];
    const float* Wih  = (const float*)d_in[2];
    const float* Whh  = (const float*)d_in[3];
    const float* bih  = (const float*)d_in[4];
    const float* bhh  = (const float*)d_in[5];
    const float* Wout = (const float*)d_in[6];
    const float* bout = (const float*)d_in[7];
    float* out = (float*)d_out;

    char* wsc = (char*)d_ws;
    unsigned short* hbuf = (unsigned short*)wsc;
    float*    hbar  = (float*)(wsc + 524288);
    unsigned* flags = (unsigned*)(wsc + 540672);
    unsigned* dctr  = (unsigned*)(wsc + 544768);

    hipMemsetAsync(d_ws, 0, WS_NEED, stream);

    zgru_persistent<<<dim3(256), dim3(256), 0, stream>>>(
        x, lens, Wih, Whh, bih, bhh, Wout, bout, out, hbuf, hbar, flags, dctr);
}